// Round 13
// baseline (215.740 us; speedup 1.0000x reference)
//
#include <hip/hip_runtime.h>
#include <hip/hip_bf16.h>
#include <math.h>

typedef __attribute__((ext_vector_type(8))) short short8;
typedef __attribute__((ext_vector_type(4))) float f32x4;

__device__ __forceinline__ unsigned short f2bf(float f) {
    union { float f; unsigned u; } x; x.f = f;
    unsigned r = x.u + 0x7FFF + ((x.u >> 16) & 1);
    return (unsigned short)(r >> 16);
}

__device__ __forceinline__ unsigned pk2bf(float a, float b) {
    union { __hip_bfloat162 h; unsigned u; } x;
    x.h = __float22bfloat162_rn(make_float2(a, b));
    return x.u;
}

__device__ __forceinline__ short8 mk8(uint2 a, uint2 b) {
    union { uint2 u[2]; short8 s; } x;
    x.u[0] = a; x.u[1] = b;
    return x.s;
}

__device__ __forceinline__ short8 pack8(const unsigned short* e) {
    union { unsigned u[4]; short8 s; } x;
    x.u[0] = (unsigned)e[0] | ((unsigned)e[1] << 16);
    x.u[1] = (unsigned)e[2] | ((unsigned)e[3] << 16);
    x.u[2] = (unsigned)e[4] | ((unsigned)e[5] << 16);
    x.u[3] = (unsigned)e[6] | ((unsigned)e[7] << 16);
    return x.s;
}

// ---------------- Fused single kernel: conv1+conv2+conv3+head, one block (512 thr) per image.
// All weight fragments gathered directly from raw tensors (L1/L2-hot), no prep pass.
// Column-parity-split LDS layouts; conv1/conv2 pooling fully in-lane.
// LDS 57728 B, 2 blocks/CU:
//  region0 [0,20736): xs_e/xs_o [34 rows][33 slots] uint2 (2x8976B)
//                     | h2tA/h2tB [18*18][16] bf16 (2x10368B) after conv1
//  region1 [20736,57728): h1[ich][par] 4 x [34 rows][17 slots][8 shorts] (4x9248B)
//                     | feats(17408B) + czs(512B) + zpart(2048B) + partl(640B) after conv2
__global__ __launch_bounds__(512, 4) void k_fused(
    const float* __restrict__ x,
    const float* __restrict__ w1,
    const float* __restrict__ g1, const float* __restrict__ be1,
    const float* __restrict__ m1, const float* __restrict__ v1, const float* __restrict__ cb1,
    const float* __restrict__ w2,
    const float* __restrict__ g2, const float* __restrict__ be2,
    const float* __restrict__ m2, const float* __restrict__ v2, const float* __restrict__ cb2,
    const float* __restrict__ w3,
    const float* __restrict__ g3, const float* __restrict__ be3,
    const float* __restrict__ m3, const float* __restrict__ v3, const float* __restrict__ cb3,
    const float* __restrict__ pjw, const float* __restrict__ pjb,
    const float* __restrict__ cw, const float* __restrict__ cbias,
    float* __restrict__ out)
{
    __shared__ __align__(16) unsigned char smem[57728];
    uint2* xse = (uint2*)smem;
    uint2* xso = xse + 34 * 33;
    unsigned short* h2tA = (unsigned short*)smem;
    unsigned short* h2tB = (unsigned short*)(smem + 10368);
    unsigned short* h1s  = (unsigned short*)(smem + 20736);
    float* feats = (float*)(smem + 20736);
    float* czs   = (float*)(smem + 20736 + 17408);
    float* zpart = czs + 128;
    float* partl = zpart + 512;

    int b = blockIdx.x, t = threadIdx.x;
    int lane = t & 63, w = t >> 6, q = lane >> 4, xl = lane & 15;
    const float* img = x + (size_t)b * 12288;

    // zero h1 borders
    if (t < 264) {
        int arr = t & 3, idx = t >> 2;
        int row, slot;
        if (idx < 17)      { row = 0;        slot = idx; }
        else if (idx < 34) { row = 33;       slot = idx - 17; }
        else               { row = idx - 33; slot = (arr & 1) ? 0 : 16; }
        uint4 z = {0u, 0u, 0u, 0u};
        *(uint4*)(h1s + arr * 4624 + (row * 17 + slot) * 8) = z;
    }

    // ======== conv1 A-frags + bn consts, gathered from raw tensors ========
    short8 A10, A11;
    {
        unsigned short e[8];
        #pragma unroll
        for (int j = 0; j < 8; ++j) {
            int ic = j & 3, tap = q * 2 + (j >> 2);
            e[j] = (ic < 3) ? f2bf(w1[(xl * 3 + ic) * 9 + tap]) : (unsigned short)0;
        }
        A10 = pack8(e);
        #pragma unroll
        for (int j = 0; j < 8; ++j)
            e[j] = (q == 0 && j < 3) ? f2bf(w1[(xl * 3 + j) * 9 + 8]) : (unsigned short)0;
        A11 = pack8(e);
    }
    int t0 = 2 * q, t1 = 2 * q + 1;
    int dy0 = t0 / 3 - 1, dx0 = t0 % 3 - 1;
    int dy1 = t1 / 3 - 1, dx1 = t1 % 3 - 1;
    float inv1[4], bs1[4];
    #pragma unroll
    for (int reg = 0; reg < 4; ++reg) {
        int oc = q * 4 + reg;
        float inv = g1[oc] * rsqrtf(v1[oc] + 1e-5f);
        inv1[reg] = inv;
        bs1[reg]  = (cb1[oc] - m1[oc]) * inv + be1[oc];
    }

    // ======== conv1: 3->16, pool -> h1[ich][par] (shuffle-free pooling) ========
    #pragma unroll 1
    for (int h = 0; h < 2; ++h) {
        int y0 = h * 32 - 1;
        #pragma unroll 1
        for (int i = 0; i < 5; ++i) {
            int idx = t + i * 512;
            if (idx < 2244) {
                int y = idx / 66, xx = idx - y * 66;
                int c = xx - 1;
                int gy = y0 + y;
                float v0 = 0.f, v1v = 0.f, v2v = 0.f;
                if ((unsigned)gy < 64u && (unsigned)c < 64u) {
                    const float* pb = img + gy * 64 + c;
                    v0 = pb[0]; v1v = pb[4096]; v2v = pb[8192];
                }
                uint2 pk;
                pk.x = pk2bf(v0, v1v);
                pk.y = pk2bf(v2v, 0.f);
                int par = c & 1, slot = (c + par) >> 1;
                (par ? xso : xse)[y * 33 + slot] = pk;
            }
        }
        __syncthreads();
        unsigned* h1wbase = (unsigned*)(h1s + (q >> 1) * 2 * 4624);
        #pragma unroll 1
        for (int xTp = 0; xTp < 2; ++xTp) {
            int X = xTp * 16 + xl;
            float pv[4], vph[4];
            #pragma unroll
            for (int r = 0; r < 4; ++r) {
                int ly = w * 4 + r + 1;
                #pragma unroll
                for (int ph = 0; ph < 2; ++ph) {
                    int e0 = ph + dx0, e1 = ph + dx1, e2 = ph + 1;
                    const uint2* p0 = (e0 & 1) ? xso : xse;
                    const uint2* p1 = (e1 & 1) ? xso : xse;
                    const uint2* p2 = (e2 & 1) ? xso : xse;
                    uint2 ua = p0[(ly + dy0) * 33 + X + ((e0 + 1) >> 1)];
                    uint2 ub = p1[(ly + dy1) * 33 + X + ((e1 + 1) >> 1)];
                    uint2 uc = p2[(ly + 1) * 33 + X + ((e2 + 1) >> 1)];
                    f32x4 acc = (f32x4){0.f, 0.f, 0.f, 0.f};
                    acc = __builtin_amdgcn_mfma_f32_16x16x32_bf16(A10, mk8(ua, ub), acc, 0, 0, 0);
                    acc = __builtin_amdgcn_mfma_f32_16x16x32_bf16(A11, mk8(uc, uc), acc, 0, 0, 0);
                    #pragma unroll
                    for (int reg = 0; reg < 4; ++reg) {
                        float val = fmaxf(acc[reg] * inv1[reg] + bs1[reg], 0.f);
                        vph[reg] = ph ? fmaxf(vph[reg], val) : val;
                    }
                }
                if (r & 1) {
                    int py = h * 16 + w * 2 + (r >> 1);
                    int par = X & 1, slot = (X >> 1) + par;
                    unsigned* hp = h1wbase + par * 2312
                                   + ((py + 1) * 17 + slot) * 4 + (q & 1) * 2;
                    hp[0] = pk2bf(fmaxf(vph[0], pv[0]), fmaxf(vph[1], pv[1]));
                    hp[1] = pk2bf(fmaxf(vph[2], pv[2]), fmaxf(vph[3], pv[3]));
                } else {
                    #pragma unroll
                    for (int reg = 0; reg < 4; ++reg) pv[reg] = vph[reg];
                }
            }
        }
        __syncthreads();
    }

    // zero h2t borders (xs dead) -- read only after next barrier
    if (t < 264) {
        int idx = t >> 1, half = t & 1;
        int y, xx;
        if (idx < 18)      { y = 0;        xx = idx; }
        else if (idx < 36) { y = 17;       xx = idx - 18; }
        else if (idx < 52) { y = idx - 35; xx = 0; }
        else if (idx < 68) { y = idx - 51; xx = 17; }
        else { y = -1; xx = 0; }
        if (y >= 0) {
            uint4 z = {0u, 0u, 0u, 0u};
            int pos = y * 18 + xx;
            *(uint4*)((half ? h2tB : h2tA) + pos * 16) = z;
            *(uint4*)((half ? h2tB : h2tA) + pos * 16 + 8) = z;
        }
    }

    // ======== conv2: 16->32, pool -> h2t (shuffle-free pooling, parity reads) ========
    {
        // A-frags: A2[s][o] element j: tap = s*2 + (q>>1), ic = (q&1)*8 + j, oc = o*16 + xl
        short8 A2[5][2];
        int tps = q >> 1, icb = (q & 1) * 8;
        #pragma unroll
        for (int s = 0; s < 5; ++s)
            #pragma unroll
            for (int o = 0; o < 2; ++o) {
                int tp = s * 2 + tps;
                unsigned short e[8];
                if (tp < 9) {
                    const float* wsrc = w2 + (((o * 16 + xl) * 16 + icb) * 9) + tp;
                    #pragma unroll
                    for (int j = 0; j < 8; ++j) e[j] = f2bf(wsrc[j * 9]);
                } else {
                    #pragma unroll
                    for (int j = 0; j < 8; ++j) e[j] = 0;
                }
                A2[s][o] = pack8(e);
            }
        int dyA[5], dxA[5];
        #pragma unroll
        for (int s = 0; s < 5; ++s) {
            int tp = s * 2 + tps; if (tp > 8) tp = 8;
            int d3 = tp / 3;
            dyA[s] = d3 - 1; dxA[s] = tp - d3 * 3 - 1;
        }
        const unsigned short* hb = h1s + (q & 1) * 2 * 4624;
        f32x4 acc[4][2][2];   // [r][phase][oT]
        #pragma unroll
        for (int r = 0; r < 4; ++r)
            #pragma unroll
            for (int ph = 0; ph < 2; ++ph)
                #pragma unroll
                for (int o = 0; o < 2; ++o)
                    acc[r][ph][o] = (f32x4){0.f, 0.f, 0.f, 0.f};
        #pragma unroll
        for (int r = 0; r < 4; ++r) {
            int ry = w * 4 + r;
            #pragma unroll
            for (int ph = 0; ph < 2; ++ph) {
                #pragma unroll
                for (int s = 0; s < 5; ++s) {
                    int e = ph + dxA[s];
                    int row = ry + dyA[s] + 1;
                    int slot = xl + ((e + 1) >> 1);
                    const unsigned short* src = hb + (e & 1) * 4624;
                    short8 B = *(const short8*)(src + (row * 17 + slot) * 8);
                    acc[r][ph][0] = __builtin_amdgcn_mfma_f32_16x16x32_bf16(A2[s][0], B, acc[r][ph][0], 0, 0, 0);
                    acc[r][ph][1] = __builtin_amdgcn_mfma_f32_16x16x32_bf16(A2[s][1], B, acc[r][ph][1], 0, 0, 0);
                }
            }
        }
        #pragma unroll
        for (int oT = 0; oT < 2; ++oT)
            #pragma unroll
            for (int rp = 0; rp < 2; ++rp) {
                float vo[4];
                #pragma unroll
                for (int reg = 0; reg < 4; ++reg) {
                    int oc = oT * 16 + q * 4 + reg;
                    float iv = g2[oc] * rsqrtf(v2[oc] + 1e-5f);
                    float bv = (cb2[oc] - m2[oc]) * iv + be2[oc];
                    float v00 = fmaxf(acc[rp * 2][0][oT][reg] * iv + bv, 0.f);
                    float v01 = fmaxf(acc[rp * 2][1][oT][reg] * iv + bv, 0.f);
                    float v10 = fmaxf(acc[rp * 2 + 1][0][oT][reg] * iv + bv, 0.f);
                    float v11 = fmaxf(acc[rp * 2 + 1][1][oT][reg] * iv + bv, 0.f);
                    vo[reg] = fmaxf(fmaxf(v00, v01), fmaxf(v10, v11));
                }
                int pos = (w * 2 + rp + 1) * 18 + (xl + 1);
                unsigned* hp = (unsigned*)(oT ? h2tB : h2tA) + pos * 8 + q * 2;
                hp[0] = pk2bf(vo[0], vo[1]);
                hp[1] = pk2bf(vo[2], vo[3]);
            }
    }
    __syncthreads();

    // ======== conv3: 32->64, pool -> feats [64][68] f32 ========
    {
        int op = w & 1, rg = w >> 1;
        const unsigned short* h2r = (q < 2) ? h2tA : h2tB;
        // A3[tap][tt] element j: ic = q*8 + j, oc = (op*2+tt)*16 + xl
        short8 A3[9][2];
        #pragma unroll
        for (int tap = 0; tap < 9; ++tap)
            #pragma unroll
            for (int tt = 0; tt < 2; ++tt) {
                const float* wsrc = w3 + ((((op * 2 + tt) * 16 + xl) * 32 + q * 8) * 9) + tap;
                unsigned short e[8];
                #pragma unroll
                for (int j = 0; j < 8; ++j) e[j] = f2bf(wsrc[j * 9]);
                A3[tap][tt] = pack8(e);
            }
        f32x4 acc[4][2];
        #pragma unroll
        for (int r = 0; r < 4; ++r) {
            acc[r][0] = (f32x4){0.f, 0.f, 0.f, 0.f};
            acc[r][1] = (f32x4){0.f, 0.f, 0.f, 0.f};
        }
        #pragma unroll
        for (int r = 0; r < 4; ++r) {
            int ry = rg * 4 + r + 1;
            #pragma unroll
            for (int tap = 0; tap < 9; ++tap) {
                int pos = (ry + tap / 3 - 1) * 18 + xl + (tap % 3);
                short8 B = *(const short8*)(h2r + pos * 16 + (q & 1) * 8);
                acc[r][0] = __builtin_amdgcn_mfma_f32_16x16x32_bf16(A3[tap][0], B, acc[r][0], 0, 0, 0);
                acc[r][1] = __builtin_amdgcn_mfma_f32_16x16x32_bf16(A3[tap][1], B, acc[r][1], 0, 0, 0);
            }
        }
        #pragma unroll
        for (int tt = 0; tt < 2; ++tt)
            #pragma unroll
            for (int reg = 0; reg < 4; ++reg) {
                int oc = (op * 2 + tt) * 16 + q * 4 + reg;
                float iv = g3[oc] * rsqrtf(v3[oc] + 1e-5f);
                float bv = (cb3[oc] - m3[oc]) * iv + be3[oc];
                #pragma unroll
                for (int rp = 0; rp < 2; ++rp) {
                    float v0 = fmaxf(acc[rp * 2][tt][reg] * iv + bv, 0.f);
                    float v1 = fmaxf(acc[rp * 2 + 1][tt][reg] * iv + bv, 0.f);
                    float vm = fmaxf(v0, v1);
                    float vv = fmaxf(vm, __shfl_xor(vm, 1, 64));
                    if (!(lane & 1))
                        feats[oc * 68 + (rg * 2 + rp) * 8 + (xl >> 1)] = vv;
                }
            }
    }
    __syncthreads();

    // ======== head: projection spread over all 512 threads (4-way c-split) ========
    {
        int g = t >> 2, p = t & 3;
        int k = g >> 3, d = g & 7;
        const float* wsrc = pjw + k * 2048 + (p * 64) * 8 + d;   // stride 8 floats per pos
        const float* fsrc = &feats[(k * 4 + p) * 68];
        float za = 0.f, zb = 0.f;
        #pragma unroll 8
        for (int pos = 0; pos < 64; pos += 2) {
            za = fmaf(wsrc[pos * 8],     fsrc[pos],     za);
            zb = fmaf(wsrc[pos * 8 + 8], fsrc[pos + 1], zb);
        }
        zpart[t] = za + zb;
    }
    __syncthreads();
    if (t < 128) {
        int k = t >> 3, d = t & 7;
        float z = (zpart[t * 4] + zpart[t * 4 + 1]) + (zpart[t * 4 + 2] + zpart[t * 4 + 3])
                  + pjb[k * 8 + d];
        czs[k * 8 + d] = cosf(0.5f * tanhf(z));
    }
    __syncthreads();
    if (t < 160) {
        int k = t / 10, c = t - (t / 10) * 10;
        float cz[8];
        #pragma unroll
        for (int i = 0; i < 8; ++i) cz[i] = czs[k * 8 + i];
        const float* cwp = cw + c * 576 + k * 36;
        float s = 0.f;
        float pp = 1.f;
        #pragma unroll
        for (int i = 0; i < 8; ++i) { pp *= cz[i]; s = fmaf(pp, cwp[i], s); }
        int cnt = 8;
        #pragma unroll
        for (int i = 0; i < 8; ++i) {
            float p2 = 1.f;
            #pragma unroll
            for (int j = i + 1; j < 8; ++j) { p2 *= cz[j]; s = fmaf(p2, cwp[cnt++], s); }
        }
        partl[k * 10 + c] = s;
    }
    __syncthreads();
    if (t < 10) {
        float s = cbias[t];
        #pragma unroll
        for (int k = 0; k < 16; ++k) s += partl[k * 10 + t];
        out[b * 10 + t] = s;
    }
}

extern "C" void kernel_launch(void* const* d_in, const int* in_sizes, int n_in,
                              void* d_out, int out_size, void* d_ws, size_t ws_size,
                              hipStream_t stream) {
    const float* x     = (const float*)d_in[0];
    const float* c1w   = (const float*)d_in[1];
    const float* c1b   = (const float*)d_in[2];
    const float* b1g   = (const float*)d_in[3];
    const float* b1b   = (const float*)d_in[4];
    const float* b1m   = (const float*)d_in[5];
    const float* b1v   = (const float*)d_in[6];
    const float* c2w   = (const float*)d_in[7];
    const float* c2b   = (const float*)d_in[8];
    const float* b2g   = (const float*)d_in[9];
    const float* b2b   = (const float*)d_in[10];
    const float* b2m   = (const float*)d_in[11];
    const float* b2v   = (const float*)d_in[12];
    const float* c3w   = (const float*)d_in[13];
    const float* c3b   = (const float*)d_in[14];
    const float* b3g   = (const float*)d_in[15];
    const float* b3b   = (const float*)d_in[16];
    const float* b3m   = (const float*)d_in[17];
    const float* b3v   = (const float*)d_in[18];
    const float* pjw   = (const float*)d_in[19];
    const float* pjb   = (const float*)d_in[20];
    const float* cw    = (const float*)d_in[21];
    const float* cbias = (const float*)d_in[22];
    float* outp = (float*)d_out;

    k_fused<<<512, 512, 0, stream>>>(x,
        c1w, b1g, b1b, b1m, b1v, c1b,
        c2w, b2g, b2b, b2m, b2v, c2b,
        c3w, b3g, b3b, b3m, b3v, c3b,
        pjw, pjb, cw, cbias, outp);
}

// Round 14
// 135.821 us; speedup vs baseline: 1.5884x; 1.5884x over previous
//
#include <hip/hip_runtime.h>
#include <hip/hip_bf16.h>
#include <math.h>

typedef __attribute__((ext_vector_type(8))) short short8;
typedef __attribute__((ext_vector_type(4))) float f32x4;

__device__ __forceinline__ unsigned short f2bf(float f) {
    union { float f; unsigned u; } x; x.f = f;
    unsigned r = x.u + 0x7FFF + ((x.u >> 16) & 1);
    return (unsigned short)(r >> 16);
}

// hardware packed f32x2 -> bf16x2 (low = a, high = b)
__device__ __forceinline__ unsigned pk2bf(float a, float b) {
    union { __hip_bfloat162 h; unsigned u; } x;
    x.h = __float22bfloat162_rn(make_float2(a, b));
    return x.u;
}

__device__ __forceinline__ short8 mk8(uint2 a, uint2 b) {
    union { uint2 u[2]; short8 s; } x;
    x.u[0] = a; x.u[1] = b;
    return x.s;
}

// ---------------- prep: weights -> MFMA A-frag order (bf16); bn consts; pjw transpose
// wp2[s<5][ocT<2][lane<64][j<8]: k=(lane>>4)*8+j -> (tap=s*2+(k>>4), ic=k&15)
// wp3[tap<9][o<4][lane<64][j<8]: oc=o*16+(lane&15), ic=(lane>>4)*8+j
// wp1[s<2][lane<64][j<8]: s0: k=tap*4+ic (taps 0..7); s1: k<3 -> ic of tap8
__global__ void k_prep(const float* __restrict__ w2, const float* __restrict__ w3,
    const float* g2, const float* be2, const float* m2, const float* v2, const float* cb2,
    const float* g3, const float* be3, const float* m3, const float* v3, const float* cb3,
    const float* __restrict__ w1,
    const float* g1, const float* be1, const float* m1, const float* v1, const float* cb1,
    const float* __restrict__ pjw,
    unsigned short* __restrict__ wp2, unsigned short* __restrict__ wp3,
    unsigned short* __restrict__ wp1,
    float* __restrict__ cst2, float* __restrict__ cst3, float* __restrict__ cst1,
    float* __restrict__ pjwt)
{
    int tid = blockIdx.x * 256 + threadIdx.x;
    if (tid < 5120) {
        int j = tid & 7, lane = (tid >> 3) & 63, o = (tid >> 9) & 1, s = tid >> 10;
        int kl = ((lane >> 4) << 3) + j;
        int tp = s * 2 + (kl >> 4);
        int ic = kl & 15;
        int oc = o * 16 + (lane & 15);
        float val = (tp < 9) ? w2[(oc * 16 + ic) * 9 + tp] : 0.f;
        wp2[tid] = f2bf(val);
    } else if (tid < 23552) {
        int idx = tid - 5120;
        int j = idx & 7, lane = (idx >> 3) & 63, o = (idx >> 9) & 3, tap = idx >> 11;
        int ic = ((lane >> 4) << 3) + j;
        int oc = o * 16 + (lane & 15);
        wp3[idx] = f2bf(w3[(oc * 32 + ic) * 9 + tap]);
    } else if (tid < 23648) {
        int c = tid - 23552;
        if (c < 32) {
            float inv = g2[c] * rsqrtf(v2[c] + 1e-5f);
            cst2[c] = inv;
            cst2[32 + c] = (cb2[c] - m2[c]) * inv + be2[c];
        } else {
            int c3 = c - 32;
            float inv = g3[c3] * rsqrtf(v3[c3] + 1e-5f);
            cst3[c3] = inv;
            cst3[64 + c3] = (cb3[c3] - m3[c3]) * inv + be3[c3];
        }
    } else if (tid < 24672) {
        int idx = tid - 23648;
        int j = idx & 7, lane = (idx >> 3) & 63, s = (idx >> 9) & 1;
        int k = ((lane >> 4) << 3) + j;
        int oc = lane & 15;
        float val = 0.f;
        if (s == 0) {
            int tap = k >> 2, ic = k & 3;
            if (ic < 3) val = w1[(oc * 3 + ic) * 9 + tap];
        } else {
            if (k < 3) val = w1[(oc * 3 + k) * 9 + 8];
        }
        wp1[idx] = f2bf(val);
    } else if (tid < 24688) {
        int c = tid - 24672;
        float inv = g1[c] * rsqrtf(v1[c] + 1e-5f);
        cst1[c] = inv;
        cst1[16 + c] = (cb1[c] - m1[c]) * inv + be1[c];
    } else if (tid < 57456) {
        int idx = tid - 24688;
        int k = idx >> 11, d = (idx >> 8) & 7, c = idx & 255;
        pjwt[idx] = pjw[k * 2048 + c * 8 + d];
    }
}

// ---------------- Fused: conv1+conv2+conv3+head, one block (512 thr, 8 waves) per image.
// Column-parity-split layouts; pooling is fully in-lane for conv1/conv2 (zero shuffles).
// LDS 57728 B, 2 blocks/CU:
//  region0 [0,20736): xs_e/xs_o [34 rows][33 slots] uint2 (2x8976B)
//                     | h2tA/h2tB [18*18][16] bf16 (2x10368B) after conv1
//  region1 [20736,57728): h1[ich][par] 4 x [34 rows][17 slots][8 shorts] (4x9248B)
//                     | feats [64][68] f32 (17408B) + czs(512B) + part(640B) after conv2
__global__ __launch_bounds__(512, 4) void k_fused(
    const float* __restrict__ x,
    const unsigned short* __restrict__ wp1, const float* __restrict__ cst1,
    const unsigned short* __restrict__ wp2, const float* __restrict__ cst2,
    const unsigned short* __restrict__ wp3, const float* __restrict__ cst3,
    const float* __restrict__ pjwt, const float* __restrict__ pjb,
    const float* __restrict__ cw, const float* __restrict__ cbias,
    float* __restrict__ out)
{
    __shared__ __align__(16) unsigned char smem[57728];
    uint2* xse = (uint2*)smem;                    // even input cols (0,2,..,64) slot=c/2
    uint2* xso = xse + 34 * 33;                   // odd  input cols (-1,1,..,63) slot=(c+1)/2
    unsigned short* h2tA = (unsigned short*)smem;
    unsigned short* h2tB = (unsigned short*)(smem + 10368);
    unsigned short* h1s  = (unsigned short*)(smem + 20736);  // 4 arrays of 4624 shorts
    float* feats = (float*)(smem + 20736);
    float* czs   = (float*)(smem + 20736 + 17408);
    float* partl = czs + 128;

    int b = blockIdx.x, t = threadIdx.x;
    int lane = t & 63, w = t >> 6, q = lane >> 4, xl = lane & 15;
    const float* img = x + (size_t)b * 12288;

    // zero h1 borders: per array (4): row0 slots 0..16, row33 slots 0..16,
    // rows 1..32 border slot (even-par: slot16=col32; odd-par: slot0=col-1)
    if (t < 264) {
        int arr = t & 3, idx = t >> 2;
        int row, slot;
        if (idx < 17)      { row = 0;        slot = idx; }
        else if (idx < 34) { row = 33;       slot = idx - 17; }
        else               { row = idx - 33; slot = (arr & 1) ? 0 : 16; }
        uint4 z = {0u, 0u, 0u, 0u};
        *(uint4*)(h1s + arr * 4624 + (row * 17 + slot) * 8) = z;
    }

    // ======== conv1: 3->16, pool -> h1[ich][par] (shuffle-free pooling) ========
    short8 A10 = *(const short8*)(wp1 + (lane << 3));
    short8 A11 = *(const short8*)(wp1 + ((64 + lane) << 3));
    int t0 = 2 * q, t1 = 2 * q + 1;
    int dy0 = t0 / 3 - 1, dx0 = t0 % 3 - 1;
    int dy1 = t1 / 3 - 1, dx1 = t1 % 3 - 1;
    float inv1[4], bs1[4];
    #pragma unroll
    for (int reg = 0; reg < 4; ++reg) {
        inv1[reg] = cst1[q * 4 + reg];
        bs1[reg]  = cst1[16 + q * 4 + reg];
    }
    #pragma unroll 1
    for (int h = 0; h < 2; ++h) {
        int y0 = h * 32 - 1;
        #pragma unroll 1
        for (int i = 0; i < 5; ++i) {
            int idx = t + i * 512;
            if (idx < 2244) {
                int y = idx / 66, xx = idx - y * 66;
                int c = xx - 1;
                int gy = y0 + y;
                float v0 = 0.f, v1 = 0.f, v2 = 0.f;
                if ((unsigned)gy < 64u && (unsigned)c < 64u) {
                    const float* pb = img + gy * 64 + c;
                    v0 = pb[0]; v1 = pb[4096]; v2 = pb[8192];
                }
                uint2 pk;
                pk.x = pk2bf(v0, v1);
                pk.y = pk2bf(v2, 0.f);
                int par = c & 1, slot = (c + par) >> 1;
                (par ? xso : xse)[y * 33 + slot] = pk;
            }
        }
        __syncthreads();
        unsigned* h1wbase = (unsigned*)(h1s + (q >> 1) * 2 * 4624);
        #pragma unroll 1
        for (int xTp = 0; xTp < 2; ++xTp) {
            int X = xTp * 16 + xl;
            float pv[4], vph[4];
            #pragma unroll
            for (int r = 0; r < 4; ++r) {
                int ly = w * 4 + r + 1;
                #pragma unroll
                for (int ph = 0; ph < 2; ++ph) {
                    int e0 = ph + dx0, e1 = ph + dx1, e2 = ph + 1;
                    const uint2* p0 = (e0 & 1) ? xso : xse;
                    const uint2* p1 = (e1 & 1) ? xso : xse;
                    const uint2* p2 = (e2 & 1) ? xso : xse;
                    uint2 ua = p0[(ly + dy0) * 33 + X + ((e0 + 1) >> 1)];
                    uint2 ub = p1[(ly + dy1) * 33 + X + ((e1 + 1) >> 1)];
                    uint2 uc = p2[(ly + 1) * 33 + X + ((e2 + 1) >> 1)];
                    f32x4 acc = (f32x4){0.f, 0.f, 0.f, 0.f};
                    acc = __builtin_amdgcn_mfma_f32_16x16x32_bf16(A10, mk8(ua, ub), acc, 0, 0, 0);
                    acc = __builtin_amdgcn_mfma_f32_16x16x32_bf16(A11, mk8(uc, uc), acc, 0, 0, 0);
                    #pragma unroll
                    for (int reg = 0; reg < 4; ++reg) {
                        float val = fmaxf(acc[reg] * inv1[reg] + bs1[reg], 0.f);
                        vph[reg] = ph ? fmaxf(vph[reg], val) : val;
                    }
                }
                if (r & 1) {
                    int py = h * 16 + w * 2 + (r >> 1);
                    int par = X & 1, slot = (X >> 1) + par;
                    unsigned* hp = h1wbase + par * 2312   // 4624 shorts = 2312 unsigneds
                                   + ((py + 1) * 17 + slot) * 4 + (q & 1) * 2;
                    hp[0] = pk2bf(fmaxf(vph[0], pv[0]), fmaxf(vph[1], pv[1]));
                    hp[1] = pk2bf(fmaxf(vph[2], pv[2]), fmaxf(vph[3], pv[3]));
                } else {
                    #pragma unroll
                    for (int reg = 0; reg < 4; ++reg) pv[reg] = vph[reg];
                }
            }
        }
        __syncthreads();
    }

    // zero h2t borders (xs dead) -- read only after next barrier
    if (t < 264) {
        int idx = t >> 1, half = t & 1;
        int y, xx;
        if (idx < 18)      { y = 0;        xx = idx; }
        else if (idx < 36) { y = 17;       xx = idx - 18; }
        else if (idx < 52) { y = idx - 35; xx = 0; }
        else if (idx < 68) { y = idx - 51; xx = 17; }
        else { y = -1; xx = 0; }
        if (y >= 0) {
            uint4 z = {0u, 0u, 0u, 0u};
            int pos = y * 18 + xx;
            *(uint4*)((half ? h2tB : h2tA) + pos * 16) = z;
            *(uint4*)((half ? h2tB : h2tA) + pos * 16 + 8) = z;
        }
    }

    // ======== conv2: 16->32, pool -> h2t (shuffle-free pooling, parity reads) ========
    {
        short8 A2[5][2];
        #pragma unroll
        for (int s = 0; s < 5; ++s)
            #pragma unroll
            for (int o = 0; o < 2; ++o)
                A2[s][o] = *(const short8*)(wp2 + (((s * 2 + o) * 64 + lane) << 3));
        int dyA[5], dxA[5];
        #pragma unroll
        for (int s = 0; s < 5; ++s) {
            int tp = s * 2 + (q >> 1); if (tp > 8) tp = 8;
            int d3 = tp / 3;
            dyA[s] = d3 - 1; dxA[s] = tp - d3 * 3 - 1;
        }
        const unsigned short* hb = h1s + (q & 1) * 2 * 4624;  // this quad's ic-half, par0
        f32x4 acc[4][2][2];   // [r][phase][oT]
        #pragma unroll
        for (int r = 0; r < 4; ++r)
            #pragma unroll
            for (int ph = 0; ph < 2; ++ph)
                #pragma unroll
                for (int o = 0; o < 2; ++o)
                    acc[r][ph][o] = (f32x4){0.f, 0.f, 0.f, 0.f};
        #pragma unroll
        for (int r = 0; r < 4; ++r) {
            int ry = w * 4 + r;
            #pragma unroll
            for (int ph = 0; ph < 2; ++ph) {
                #pragma unroll
                for (int s = 0; s < 5; ++s) {
                    int e = ph + dxA[s];
                    int row = ry + dyA[s] + 1;
                    int slot = xl + ((e + 1) >> 1);
                    const unsigned short* src = hb + (e & 1) * 4624;
                    short8 B = *(const short8*)(src + (row * 17 + slot) * 8);
                    acc[r][ph][0] = __builtin_amdgcn_mfma_f32_16x16x32_bf16(A2[s][0], B, acc[r][ph][0], 0, 0, 0);
                    acc[r][ph][1] = __builtin_amdgcn_mfma_f32_16x16x32_bf16(A2[s][1], B, acc[r][ph][1], 0, 0, 0);
                }
            }
        }
        #pragma unroll
        for (int oT = 0; oT < 2; ++oT)
            #pragma unroll
            for (int rp = 0; rp < 2; ++rp) {
                float vo[4];
                #pragma unroll
                for (int reg = 0; reg < 4; ++reg) {
                    int oc = oT * 16 + q * 4 + reg;
                    float iv = cst2[oc], bv = cst2[32 + oc];
                    float v00 = fmaxf(acc[rp * 2][0][oT][reg] * iv + bv, 0.f);
                    float v01 = fmaxf(acc[rp * 2][1][oT][reg] * iv + bv, 0.f);
                    float v10 = fmaxf(acc[rp * 2 + 1][0][oT][reg] * iv + bv, 0.f);
                    float v11 = fmaxf(acc[rp * 2 + 1][1][oT][reg] * iv + bv, 0.f);
                    vo[reg] = fmaxf(fmaxf(v00, v01), fmaxf(v10, v11));
                }
                int pos = (w * 2 + rp + 1) * 18 + (xl + 1);
                unsigned* hp = (unsigned*)(oT ? h2tB : h2tA) + pos * 8 + q * 2;
                hp[0] = pk2bf(vo[0], vo[1]);
                hp[1] = pk2bf(vo[2], vo[3]);
            }
    }
    __syncthreads();

    // ======== conv3: 32->64, pool -> feats [64][68] f32 ========
    {
        int op = w & 1, rg = w >> 1;
        const unsigned short* h2r = (q < 2) ? h2tA : h2tB;
        short8 A3[9][2];
        #pragma unroll
        for (int tap = 0; tap < 9; ++tap)
            #pragma unroll
            for (int tt = 0; tt < 2; ++tt)
                A3[tap][tt] = *(const short8*)(wp3 + (((tap * 4 + op * 2 + tt) * 64 + lane) << 3));
        f32x4 acc[4][2];
        #pragma unroll
        for (int r = 0; r < 4; ++r) {
            acc[r][0] = (f32x4){0.f, 0.f, 0.f, 0.f};
            acc[r][1] = (f32x4){0.f, 0.f, 0.f, 0.f};
        }
        #pragma unroll
        for (int r = 0; r < 4; ++r) {
            int ry = rg * 4 + r + 1;
            #pragma unroll
            for (int tap = 0; tap < 9; ++tap) {
                int pos = (ry + tap / 3 - 1) * 18 + xl + (tap % 3);
                short8 B = *(const short8*)(h2r + pos * 16 + (q & 1) * 8);
                acc[r][0] = __builtin_amdgcn_mfma_f32_16x16x32_bf16(A3[tap][0], B, acc[r][0], 0, 0, 0);
                acc[r][1] = __builtin_amdgcn_mfma_f32_16x16x32_bf16(A3[tap][1], B, acc[r][1], 0, 0, 0);
            }
        }
        #pragma unroll
        for (int tt = 0; tt < 2; ++tt)
            #pragma unroll
            for (int reg = 0; reg < 4; ++reg) {
                int oc = (op * 2 + tt) * 16 + q * 4 + reg;
                float iv = cst3[oc], bv = cst3[64 + oc];
                #pragma unroll
                for (int rp = 0; rp < 2; ++rp) {
                    float v0 = fmaxf(acc[rp * 2][tt][reg] * iv + bv, 0.f);
                    float v1 = fmaxf(acc[rp * 2 + 1][tt][reg] * iv + bv, 0.f);
                    float vm = fmaxf(v0, v1);
                    float vv = fmaxf(vm, __shfl_xor(vm, 1, 64));
                    if (!(lane & 1))
                        feats[oc * 68 + (rg * 2 + rp) * 8 + (xl >> 1)] = vv;
                }
            }
    }
    __syncthreads();

    // ======== head: projection + tanh + analytic quantum map + classifier ========
    if (t < 128) {
        int k = t >> 3, d = t & 7;
        const float4* wrow = (const float4*)(pjwt + ((k * 8 + d) << 8));
        float zacc = 0.f;
        #pragma unroll 4
        for (int i = 0; i < 64; ++i) {
            int c4 = (i + k) & 63;
            float4 wv = wrow[c4];
            const float* fp = &feats[(k * 4 + (c4 >> 4)) * 68 + 4 * (c4 & 15)];
            float4 fv = *(const float4*)fp;
            zacc = fmaf(wv.x, fv.x, zacc);
            zacc = fmaf(wv.y, fv.y, zacc);
            zacc = fmaf(wv.z, fv.z, zacc);
            zacc = fmaf(wv.w, fv.w, zacc);
        }
        float z = zacc + pjb[k * 8 + d];
        czs[k * 8 + d] = cosf(0.5f * tanhf(z));
    }
    __syncthreads();
    if (t < 160) {
        int k = t / 10, c = t - (t / 10) * 10;
        float cz[8];
        #pragma unroll
        for (int i = 0; i < 8; ++i) cz[i] = czs[k * 8 + i];
        const float* cwp = cw + c * 576 + k * 36;
        float s = 0.f;
        float pp = 1.f;
        #pragma unroll
        for (int i = 0; i < 8; ++i) { pp *= cz[i]; s = fmaf(pp, cwp[i], s); }
        int cnt = 8;
        #pragma unroll
        for (int i = 0; i < 8; ++i) {
            float p2 = 1.f;
            #pragma unroll
            for (int j = i + 1; j < 8; ++j) { p2 *= cz[j]; s = fmaf(p2, cwp[cnt++], s); }
        }
        partl[k * 10 + c] = s;
    }
    __syncthreads();
    if (t < 10) {
        float s = cbias[t];
        #pragma unroll
        for (int k = 0; k < 16; ++k) s += partl[k * 10 + t];
        out[b * 10 + t] = s;
    }
}

extern "C" void kernel_launch(void* const* d_in, const int* in_sizes, int n_in,
                              void* d_out, int out_size, void* d_ws, size_t ws_size,
                              hipStream_t stream) {
    const float* x     = (const float*)d_in[0];
    const float* c1w   = (const float*)d_in[1];
    const float* c1b   = (const float*)d_in[2];
    const float* b1g   = (const float*)d_in[3];
    const float* b1b   = (const float*)d_in[4];
    const float* b1m   = (const float*)d_in[5];
    const float* b1v   = (const float*)d_in[6];
    const float* c2w   = (const float*)d_in[7];
    const float* c2b   = (const float*)d_in[8];
    const float* b2g   = (const float*)d_in[9];
    const float* b2b   = (const float*)d_in[10];
    const float* b2m   = (const float*)d_in[11];
    const float* b2v   = (const float*)d_in[12];
    const float* c3w   = (const float*)d_in[13];
    const float* c3b   = (const float*)d_in[14];
    const float* b3g   = (const float*)d_in[15];
    const float* b3b   = (const float*)d_in[16];
    const float* b3m   = (const float*)d_in[17];
    const float* b3v   = (const float*)d_in[18];
    const float* pjw   = (const float*)d_in[19];
    const float* pjb   = (const float*)d_in[20];
    const float* cw    = (const float*)d_in[21];
    const float* cbias = (const float*)d_in[22];
    float* outp = (float*)d_out;

    unsigned char* prep = (unsigned char*)d_ws;
    unsigned short* wp2 = (unsigned short*)prep;                       // 5120 bf16
    unsigned short* wp3 = (unsigned short*)(prep + 16384);             // 18432 bf16
    unsigned short* wp1 = (unsigned short*)(prep + 16384 + 36864);     // 1024 bf16
    float* cst2 = (float*)(prep + 16384 + 36864 + 2048);               // 64 f
    float* cst3 = cst2 + 64;                                           // 128 f
    float* cst1 = cst3 + 128;                                          // 32 f
    float* pjwt = (float*)(prep + 16384 + 36864 + 2048 + 1024);        // 32768 f

    k_prep<<<225, 256, 0, stream>>>(c2w, c3w, b2g, b2b, b2m, b2v, c2b,
                                    b3g, b3b, b3m, b3v, c3b,
                                    c1w, b1g, b1b, b1m, b1v, c1b, pjw,
                                    wp2, wp3, wp1, cst2, cst3, cst1, pjwt);
    k_fused<<<512, 512, 0, stream>>>(x, wp1, cst1, wp2, cst2, wp3, cst3,
                                     pjwt, pjb, cw, cbias, outp);
}